// Round 3
// baseline (1122.966 us; speedup 1.0000x reference)
//
#include <hip/hip_runtime.h>

#define SG 128
#define C 32
#define NPB 250000
#define BATCH 2
#define M (BATCH * NPB)
#define BM 128
#define NTHR 256
#define NK 27
#define SLOTS 64
#define NBLK ((M + BM - 1) / BM)

// ---------------- scatter: fill voxel grid with point indices ----------------
__global__ void scatter_kernel(const int* __restrict__ coords, int* __restrict__ grid) {
    int p = blockIdx.x * blockDim.x + threadIdx.x;
    if (p >= M) return;
    int x = coords[3 * p + 0];
    int y = coords[3 * p + 1];
    int z = coords[3 * p + 2];
    int b = (p >= NPB) ? 1 : 0;
    grid[((b * SG + x) * SG + y) * SG + z] = p;
}

// ---------------- build rulebook: per (block, tap) pair lists ----------------
__global__ void build_kernel(const int* __restrict__ coords,
                             const int* __restrict__ grid,
                             int* __restrict__ cnt,
                             int* __restrict__ pairs) {
    int p = blockIdx.x * blockDim.x + threadIdx.x;
    if (p >= M) return;
    int x = coords[3 * p + 0];
    int y = coords[3 * p + 1];
    int z = coords[3 * p + 2];
    int base = (p >= NPB) ? SG * SG * SG : 0;
    int blk = p >> 7, ploc = p & 127;
#pragma unroll
    for (int k = 0; k < NK; k++) {
        if (k == 13) continue;
        int nx = x + (k / 9) - 1;
        int ny = y + ((k / 3) % 3) - 1;
        int nz = z + (k % 3) - 1;
        if ((unsigned)nx < SG && (unsigned)ny < SG && (unsigned)nz < SG) {
            int idx = grid[base + (nx * SG + ny) * SG + nz];
            if (idx >= 0) {
                int slot = atomicAdd(&cnt[blk * NK + k], 1);
                if (slot < SLOTS)
                    pairs[(blk * NK + k) * SLOTS + slot] = idx | (ploc << 19);
            }
        }
    }
}

// ---------------- sparse conv ----------------
// Block = 128 output points, ACC[128][32] in LDS (16B chunks XOR-swizzled by
// row&7). Per tap: chunks of 32 pairs; thread = (j = t>>3 pair, co4 = t&7).
// GT[32][32] swizzled; one ds_read_b128 serves 8 pairs x 8 co-groups.
// W rows read from global (L1-hot, imm-offset folded).
template <bool RELU>
__global__ __launch_bounds__(NTHR) void conv_kernel(
    const float* __restrict__ fin,    // [M][C]
    const int* __restrict__ cnt,      // [NBLK][27]
    const int* __restrict__ pairs,    // [NBLK][27][SLOTS]
    const float* __restrict__ W,      // [27][C][C]
    float* __restrict__ fout)         // [M][C]
{
    __shared__ float ACC[BM * C];   // 16 KB
    __shared__ float GT[32 * C];    // 4 KB
    __shared__ int   PL[32];
    __shared__ int   KC[NK];

    const int t = threadIdx.x;
    const int blk = blockIdx.x;
    const int pbase = blk * BM;
    const int npts = min(BM, M - pbase);

    for (int i = t; i < BM * C; i += NTHR) ACC[i] = 0.f;
    if (t < NK) KC[t] = (t == 13) ? npts : min(cnt[blk * NK + t], SLOTS);
    __syncthreads();

    const int j   = t >> 3;     // pair slot 0..31
    const int jm  = j & 7;
    const int co4 = t & 7;      // cout group
    const int co0 = co4 << 2;

    for (int k = 0; k < NK; k++) {
        const int np = KC[k];
        if (np == 0) continue;          // uniform over block
        const float* Wk = W + (k << 10);

        for (int c0 = 0; c0 < np; c0 += 32) {
            const int npc = min(32, np - c0);
            __syncthreads();            // previous chunk's compute done
            int ploc = 0;
            if (j < npc) {
                int idx;
                if (k == 13) { ploc = c0 + j; idx = pbase + ploc; }
                else {
                    int e = pairs[(blk * NK + k) * SLOTS + c0 + j];
                    idx = e & 0x7FFFF; ploc = e >> 19;
                }
                if (co4 == 0) PL[j] = ploc;
                // stage: phys chunk co4 holds logical chunk (co4 ^ jm)
                int lc = co4 ^ jm;
                *(float4*)&GT[(j << 5) + (co4 << 2)] =
                    *(const float4*)&fin[idx * C + (lc << 2)];
            }
            __syncthreads();
            if (j < npc) {
                float4 a = make_float4(0.f, 0.f, 0.f, 0.f);
#pragma unroll
                for (int ci4 = 0; ci4 < 8; ci4++) {
                    // logical chunk ci4 lives at phys (ci4 ^ jm)
                    float4 g = *(const float4*)&GT[(j << 5) + ((ci4 ^ jm) << 2)];
                    float ga[4] = {g.x, g.y, g.z, g.w};
#pragma unroll
                    for (int r = 0; r < 4; r++) {
                        float4 w = *(const float4*)&Wk[((ci4 << 2) + r) * C + co0];
                        a.x += ga[r] * w.x;
                        a.y += ga[r] * w.y;
                        a.z += ga[r] * w.z;
                        a.w += ga[r] * w.w;
                    }
                }
                ploc = PL[j];
                float4* ap = (float4*)&ACC[(ploc << 5) + ((co4 ^ (ploc & 7)) << 2)];
                float4 cur = *ap;
                cur.x += a.x; cur.y += a.y; cur.z += a.z; cur.w += a.w;
                *ap = cur;
            }
        }
    }
    __syncthreads();

    // epilogue: un-swizzle, coalesced float4 writes
    for (int v = t; v < npts * 8; v += NTHR) {
        int p = v >> 3, c = v & 7;
        float4 o = *(const float4*)&ACC[(p << 5) + ((c ^ (p & 7)) << 2)];
        if (RELU) {
            o.x = fmaxf(o.x, 0.f); o.y = fmaxf(o.y, 0.f);
            o.z = fmaxf(o.z, 0.f); o.w = fmaxf(o.w, 0.f);
        }
        *(float4*)&fout[(pbase + p) * C + (c << 2)] = o;
    }
}

extern "C" void kernel_launch(void* const* d_in, const int* in_sizes, int n_in,
                              void* d_out, int out_size, void* d_ws, size_t ws_size,
                              hipStream_t stream) {
    const float* features    = (const float*)d_in[0];
    const int*   coordinates = (const int*)d_in[1];
    const float* W1 = (const float*)d_in[4];
    const float* W2 = (const float*)d_in[5];
    const float* W3 = (const float*)d_in[6];
    float* out = (float*)d_out;

    char* ws = (char*)d_ws;
    const size_t GRID_BYTES  = (size_t)BATCH * SG * SG * SG * 4;     // 16.8 MB
    const size_t CNT_BYTES   = (size_t)NBLK * NK * 4;                // 0.42 MB
    const size_t PAIR_BYTES  = (size_t)NBLK * NK * SLOTS * 4;        // 27 MB
    const size_t FEAT_BYTES  = (size_t)M * C * 4;                    // 64 MB

    int*   grid  = (int*)ws;
    int*   cnt   = (int*)(ws + GRID_BYTES);
    int*   pairs = (int*)(ws + GRID_BYTES + CNT_BYTES);
    float* x1    = (float*)(ws + GRID_BYTES + CNT_BYTES + PAIR_BYTES);
    float* x2    = (float*)(ws + GRID_BYTES + CNT_BYTES + PAIR_BYTES + FEAT_BYTES);

    hipMemsetAsync(grid, 0xFF, GRID_BYTES, stream);
    hipMemsetAsync(cnt, 0, CNT_BYTES, stream);
    scatter_kernel<<<(M + 255) / 256, 256, 0, stream>>>(coordinates, grid);
    build_kernel<<<(M + 255) / 256, 256, 0, stream>>>(coordinates, grid, cnt, pairs);

    conv_kernel<true ><<<NBLK, NTHR, 0, stream>>>(features, cnt, pairs, W1, x1);
    conv_kernel<true ><<<NBLK, NTHR, 0, stream>>>(x1,       cnt, pairs, W2, x2);
    conv_kernel<false><<<NBLK, NTHR, 0, stream>>>(x2,       cnt, pairs, W3, out);
}

// Round 4
// 496.044 us; speedup vs baseline: 2.2638x; 2.2638x over previous
//
#include <hip/hip_runtime.h>

#define SG 128
#define C 32
#define NPB 250000
#define BATCH 2
#define M (BATCH * NPB)
#define NK 27

typedef __attribute__((ext_vector_type(4))) float f32x4;
typedef __attribute__((ext_vector_type(8))) short bf16x8;

union frag_u { unsigned u[4]; bf16x8 v; };

// ---------------- scatter: fill voxel grid with point indices ----------------
__global__ void scatter_kernel(const int* __restrict__ coords, int* __restrict__ grid) {
    int p = blockIdx.x * blockDim.x + threadIdx.x;
    if (p >= M) return;
    int x = coords[3 * p + 0];
    int y = coords[3 * p + 1];
    int z = coords[3 * p + 2];
    int b = (p >= NPB) ? 1 : 0;
    grid[((b * SG + x) * SG + y) * SG + z] = p;
}

// ---------------- build neighbor table nb[k][p] (self tap k=13 included) ----
__global__ void build_nb_kernel(const int* __restrict__ coords,
                                const int* __restrict__ grid,
                                int* __restrict__ nb) {
    int p = blockIdx.x * blockDim.x + threadIdx.x;
    if (p >= M) return;
    int x = coords[3 * p + 0];
    int y = coords[3 * p + 1];
    int z = coords[3 * p + 2];
    int base = (p >= NPB) ? SG * SG * SG : 0;
#pragma unroll
    for (int k = 0; k < NK; k++) {
        int nx = x + k / 9 - 1;
        int ny = y + (k / 3) % 3 - 1;
        int nz = z + (k % 3) - 1;
        int idx = -1;
        if ((unsigned)nx < SG && (unsigned)ny < SG && (unsigned)nz < SG)
            idx = grid[base + (nx * SG + ny) * SG + nz];
        nb[k * M + p] = idx;
    }
}

// ---------------- pack W into MFMA B-fragment layout, split bf16 hi/lo -------
// B-frag (16x16x32): lane l holds B[ci = 8*(l>>4)+j][co = ct*16 + (l&15)], j=0..7.
// wpk[tap][ct(2)][var(2)][lane(64)][j(8)] ushort; per-tap stride 2048 elems.
__global__ void prep_w_kernel(const float* __restrict__ W, unsigned short* __restrict__ wpk) {
    int id = blockIdx.x * blockDim.x + threadIdx.x;
    if (id >= NK * 2 * 64) return;
    int l = id & 63, ct = (id >> 6) & 1, k = id >> 7;
    int lrow = l & 15, kg = l >> 4;
    unsigned hw[4], lw[4];
#pragma unroll
    for (int jp = 0; jp < 4; jp++) {
        float v0 = W[k * 1024 + (kg * 8 + 2 * jp + 0) * 32 + ct * 16 + lrow];
        float v1 = W[k * 1024 + (kg * 8 + 2 * jp + 1) * 32 + ct * 16 + lrow];
        unsigned u0 = __float_as_uint(v0), u1 = __float_as_uint(v1);
        hw[jp] = (u0 >> 16) | (u1 & 0xFFFF0000u);
        float h0 = __uint_as_float(u0 & 0xFFFF0000u);
        float h1 = __uint_as_float(u1 & 0xFFFF0000u);
        lw[jp] = (__float_as_uint(v0 - h0) >> 16) | (__float_as_uint(v1 - h1) & 0xFFFF0000u);
    }
    unsigned* dh = (unsigned*)(wpk + k * 2048 + ((ct * 2 + 0) * 64 + l) * 8);
    unsigned* dl = (unsigned*)(wpk + k * 2048 + ((ct * 2 + 1) * 64 + l) * 8);
#pragma unroll
    for (int i = 0; i < 4; i++) { dh[i] = hw[i]; dl[i] = lw[i]; }
}

// split 8 f32 -> hi/lo bf16 fragments (truncation; lo captures the residual)
__device__ __forceinline__ void split8(f32x4 g0, f32x4 g1, frag_u& h, frag_u& lo) {
    float ga[8] = {g0[0], g0[1], g0[2], g0[3], g1[0], g1[1], g1[2], g1[3]};
#pragma unroll
    for (int jp = 0; jp < 4; jp++) {
        unsigned u0 = __float_as_uint(ga[2 * jp]), u1 = __float_as_uint(ga[2 * jp + 1]);
        h.u[jp] = (u0 >> 16) | (u1 & 0xFFFF0000u);
        float h0 = __uint_as_float(u0 & 0xFFFF0000u);
        float h1 = __uint_as_float(u1 & 0xFFFF0000u);
        lo.u[jp] = (__float_as_uint(ga[2 * jp] - h0) >> 16) |
                   (__float_as_uint(ga[2 * jp + 1] - h1) & 0xFFFF0000u);
    }
}

// ---------------- conv: wave = 32 output points, dense 27 taps, MFMA ---------
// A-frag: lane l holds A[row = l&15][ci = 8*(l>>4)+j]; D: row=4*(l>>4)+j, col=l&15.
template <bool RELU>
__global__ __launch_bounds__(256) void conv_mfma(
    const float* __restrict__ fin,          // [M][C]
    const int* __restrict__ nb,             // [NK][M]
    const unsigned short* __restrict__ wpk, // packed B-frags
    float* __restrict__ fout)               // [M][C]
{
    int t = threadIdx.x;
    int l = t & 63;
    int wbase = blockIdx.x * 128 + (t >> 6) * 32;
    if (wbase >= M) return;                 // M % 32 == 0: waves are all-or-nothing
    int lrow = l & 15, kg = l >> 4, ci0 = kg * 8;
    int row0 = wbase + lrow, row1 = row0 + 16;

    f32x4 acc00 = {0, 0, 0, 0}, acc01 = {0, 0, 0, 0};
    f32x4 acc10 = {0, 0, 0, 0}, acc11 = {0, 0, 0, 0};

    for (int k = 0; k < NK; k++) {
        const unsigned short* wb = wpk + k * 2048;
        frag_u bh0, bl0, bh1, bl1;
        bh0.v = *(const bf16x8*)(wb + (0 * 64 + l) * 8);
        bl0.v = *(const bf16x8*)(wb + (1 * 64 + l) * 8);
        bh1.v = *(const bf16x8*)(wb + (2 * 64 + l) * 8);
        bl1.v = *(const bf16x8*)(wb + (3 * 64 + l) * 8);

        int i0 = nb[k * M + row0];
        int i1 = nb[k * M + row1];

        frag_u ah0, al0, ah1, al1;
        {
            f32x4 g0 = {0, 0, 0, 0}, g1 = {0, 0, 0, 0};
            if (i0 >= 0) {
                g0 = *(const f32x4*)&fin[i0 * 32 + ci0];
                g1 = *(const f32x4*)&fin[i0 * 32 + ci0 + 4];
            }
            split8(g0, g1, ah0, al0);
        }
        {
            f32x4 g0 = {0, 0, 0, 0}, g1 = {0, 0, 0, 0};
            if (i1 >= 0) {
                g0 = *(const f32x4*)&fin[i1 * 32 + ci0];
                g1 = *(const f32x4*)&fin[i1 * 32 + ci0 + 4];
            }
            split8(g0, g1, ah1, al1);
        }

        acc00 = __builtin_amdgcn_mfma_f32_16x16x32_bf16(ah0.v, bh0.v, acc00, 0, 0, 0);
        acc01 = __builtin_amdgcn_mfma_f32_16x16x32_bf16(ah0.v, bh1.v, acc01, 0, 0, 0);
        acc10 = __builtin_amdgcn_mfma_f32_16x16x32_bf16(ah1.v, bh0.v, acc10, 0, 0, 0);
        acc11 = __builtin_amdgcn_mfma_f32_16x16x32_bf16(ah1.v, bh1.v, acc11, 0, 0, 0);
        acc00 = __builtin_amdgcn_mfma_f32_16x16x32_bf16(ah0.v, bl0.v, acc00, 0, 0, 0);
        acc01 = __builtin_amdgcn_mfma_f32_16x16x32_bf16(ah0.v, bl1.v, acc01, 0, 0, 0);
        acc10 = __builtin_amdgcn_mfma_f32_16x16x32_bf16(ah1.v, bl0.v, acc10, 0, 0, 0);
        acc11 = __builtin_amdgcn_mfma_f32_16x16x32_bf16(ah1.v, bl1.v, acc11, 0, 0, 0);
        acc00 = __builtin_amdgcn_mfma_f32_16x16x32_bf16(al0.v, bh0.v, acc00, 0, 0, 0);
        acc01 = __builtin_amdgcn_mfma_f32_16x16x32_bf16(al0.v, bh1.v, acc01, 0, 0, 0);
        acc10 = __builtin_amdgcn_mfma_f32_16x16x32_bf16(al1.v, bh0.v, acc10, 0, 0, 0);
        acc11 = __builtin_amdgcn_mfma_f32_16x16x32_bf16(al1.v, bh1.v, acc11, 0, 0, 0);
    }

    // store: D[row=4*kg+j][col=lrow] per tile
#pragma unroll
    for (int rt = 0; rt < 2; rt++) {
#pragma unroll
        for (int ct = 0; ct < 2; ct++) {
            f32x4 a = rt == 0 ? (ct == 0 ? acc00 : acc01) : (ct == 0 ? acc10 : acc11);
#pragma unroll
            for (int j = 0; j < 4; j++) {
                float v = a[j];
                if (RELU) v = fmaxf(v, 0.f);
                fout[(wbase + rt * 16 + 4 * kg + j) * 32 + ct * 16 + lrow] = v;
            }
        }
    }
}

extern "C" void kernel_launch(void* const* d_in, const int* in_sizes, int n_in,
                              void* d_out, int out_size, void* d_ws, size_t ws_size,
                              hipStream_t stream) {
    const float* features    = (const float*)d_in[0];
    const int*   coordinates = (const int*)d_in[1];
    const float* W1 = (const float*)d_in[4];
    const float* W2 = (const float*)d_in[5];
    const float* W3 = (const float*)d_in[6];
    float* out = (float*)d_out;

    char* ws = (char*)d_ws;
    const size_t GRID_BYTES = (size_t)BATCH * SG * SG * SG * 4;   // 16.78 MB
    const size_t NB_BYTES   = (size_t)NK * M * 4;                 // 54.0 MB
    const size_t WPK_BYTES  = (size_t)NK * 2048 * 2;              // 110,592 B

    int* grid = (int*)ws;
    int* nbl  = (int*)(ws + GRID_BYTES);
    unsigned short* wpk1 = (unsigned short*)(ws + GRID_BYTES + NB_BYTES);
    unsigned short* wpk2 = (unsigned short*)(ws + GRID_BYTES + NB_BYTES + WPK_BYTES);
    unsigned short* wpk3 = (unsigned short*)(ws + GRID_BYTES + NB_BYTES + 2 * WPK_BYTES);
    float* x1 = (float*)(ws + GRID_BYTES + NB_BYTES + 3 * WPK_BYTES);  // 64 MB
    // buffers: layer1 features->out, layer2 out->x1, layer3 x1->out (d_out reused)

    hipMemsetAsync(grid, 0xFF, GRID_BYTES, stream);
    scatter_kernel<<<(M + 255) / 256, 256, 0, stream>>>(coordinates, grid);
    build_nb_kernel<<<(M + 255) / 256, 256, 0, stream>>>(coordinates, grid, nbl);

    const int PW = NK * 2 * 64;
    prep_w_kernel<<<(PW + 255) / 256, 256, 0, stream>>>(W1, wpk1);
    prep_w_kernel<<<(PW + 255) / 256, 256, 0, stream>>>(W2, wpk2);
    prep_w_kernel<<<(PW + 255) / 256, 256, 0, stream>>>(W3, wpk3);

    const int nblk = (M + 127) / 128;
    conv_mfma<true ><<<nblk, 256, 0, stream>>>(features, nbl, wpk1, out);
    conv_mfma<true ><<<nblk, 256, 0, stream>>>(out,      nbl, wpk2, x1);
    conv_mfma<false><<<nblk, 256, 0, stream>>>(x1,       nbl, wpk3, out);
}